// Round 1
// baseline (58.376 us; speedup 1.0000x reference)
//
#include <hip/hip_runtime.h>

#define NS   48          // samples per ray
#define NSM1 47          // segments per ray
#define NC   32          // color channels
#define WPB  4           // waves (rays) per block

// ---------------- workspace init: ws[0]=+inf bits (min), ws[1]=0 (max) ----
__global__ void init_ws_kernel(unsigned int* ws) {
    ws[0] = 0x7f800000u;   // +inf  (all depths > 0, uint order == float order)
    ws[1] = 0u;
}

// ---------------- global depth min/max (depths sorted along S) ------------
__global__ void depth_minmax_kernel(const float* __restrict__ depths,
                                    unsigned int* __restrict__ ws, int nrays) {
    int t = blockIdx.x * blockDim.x + threadIdx.x;
    float mn = __uint_as_float(0x7f800000u);
    float mx = 0.0f;
    if (t < nrays) {
        mn = depths[(size_t)t * NS];
        mx = depths[(size_t)t * NS + (NS - 1)];
    }
#pragma unroll
    for (int off = 32; off; off >>= 1) {
        mn = fminf(mn, __shfl_xor(mn, off));
        mx = fmaxf(mx, __shfl_xor(mx, off));
    }
    if ((threadIdx.x & 63) == 0) {
        atomicMin(ws + 0, __float_as_uint(mn));
        atomicMax(ws + 1, __float_as_uint(mx));
    }
}

// ---------------- main ray-march compositing kernel ------------------------
__launch_bounds__(WPB * 64)
__global__ void raymarch_kernel(const float* __restrict__ colors,
                                const float* __restrict__ densities,
                                const float* __restrict__ depths,
                                const float* __restrict__ sc,
                                const unsigned int* __restrict__ ws,
                                float* __restrict__ out_rgb,
                                float* __restrict__ out_depth,
                                float* __restrict__ out_w,
                                float* __restrict__ out_xyz,
                                float* __restrict__ out_wt,
                                int nrays) {
    __shared__ float wlds[WPB][52];    // 49 used: [0]=0, [1..47]=w, [48]=0
    __shared__ float scl[WPB][146];    // 144 used: per-ray sample coords

    const int lane = threadIdx.x & 63;
    const int wv   = threadIdx.x >> 6;
    const int r    = blockIdx.x * WPB + wv;
    if (r >= nrays) return;            // grid is exact; kept for safety

    // ---- phase A: per-segment alpha / transmittance / weights -----------
    const size_t rbase = (size_t)r * NS;
    float d = 0.0f, de = 0.0f;
    if (lane < NS) {
        d  = depths[rbase + lane];
        de = densities[rbase + lane];
    }
    const float d1  = __shfl_down(d, 1);
    const float de1 = __shfl_down(de, 1);

    float alpha = 0.0f, dmid = 0.0f, f = 1.0f;
    if (lane < NSM1) {
        const float delta = d1 - d;
        dmid = 0.5f * (d + d1);
        const float x  = 0.5f * (de + de1) - 1.0f;
        const float sp = fmaxf(x, 0.0f) + log1pf(expf(-fabsf(x)));   // softplus
        alpha = 1.0f - expf(-sp * delta);
        f = 1.0f - alpha + 1e-10f;
    }

    // exclusive prefix product of f -> transmittance T[lane]
    float g = __shfl_up(f, 1);
    if (lane == 0) g = 1.0f;
#pragma unroll
    for (int off = 1; off < 64; off <<= 1) {
        const float v = __shfl_up(g, off);
        if (lane >= off) g *= v;
    }
    const float wgt = (lane < NSM1) ? alpha * g : 0.0f;

    // weight_total and depth numerator (all lanes end with the totals)
    float wt = wgt, dsum = wgt * dmid;
#pragma unroll
    for (int off = 32; off; off >>= 1) {
        wt   += __shfl_xor(wt, off);
        dsum += __shfl_xor(dsum, off);
    }

    // ---- stage per-ray LDS: weights for color coefficients + coords -----
    if (lane < NSM1) wlds[wv][lane + 1] = wgt;
    if (lane == 0) { wlds[wv][0] = 0.0f; wlds[wv][NS] = 0.0f; }
    const size_t scbase = (size_t)r * (NS * 3);
#pragma unroll
    for (int i = 0; i < 3; ++i) {
        const int idx = lane + i * 64;
        if (idx < NS * 3) scl[wv][idx] = sc[scbase + idx];
    }
    __syncthreads();

    // ---- colors: single coalesced float4 pass ----------------------------
    // rgb[c] = sum_j col[j][c] * 0.5*(w[j-1]+w[j])
    const float4* colp = (const float4*)(colors + (size_t)r * (NS * NC));
    const int soff = lane >> 3;        // sample offset within group of 8
    float4 acc = make_float4(0.f, 0.f, 0.f, 0.f);
#pragma unroll
    for (int t = 0; t < 6; ++t) {
        const int j = t * 8 + soff;
        const float a = 0.5f * (wlds[wv][j] + wlds[wv][j + 1]);
        const float4 cv = colp[t * 64 + lane];
        acc.x = fmaf(a, cv.x, acc.x);
        acc.y = fmaf(a, cv.y, acc.y);
        acc.z = fmaf(a, cv.z, acc.z);
        acc.w = fmaf(a, cv.w, acc.w);
    }
#pragma unroll
    for (int off = 8; off < 64; off <<= 1) {
        acc.x += __shfl_xor(acc.x, off);
        acc.y += __shfl_xor(acc.y, off);
        acc.z += __shfl_xor(acc.z, off);
        acc.w += __shfl_xor(acc.w, off);
    }
    if (lane < 8) {
        float4 o;
        o.x = fmaf(acc.x, 2.0f, -1.0f);
        o.y = fmaf(acc.y, 2.0f, -1.0f);
        o.z = fmaf(acc.z, 2.0f, -1.0f);
        o.w = fmaf(acc.w, 2.0f, -1.0f);
        ((float4*)out_rgb)[(size_t)r * (NC / 4) + lane] = o;
    }

    // ---- weights_out, xyz, depth, weight_total ---------------------------
    float px = 0.f, py = 0.f, pz = 0.f;
    float wout = 0.0f;
    if (lane < NSM1) {
        wout = wgt + ((lane == NSM1 - 1) ? (1.0f - wt) : 0.0f);
        const int b3 = 3 * lane;
        px = wout * (0.5f * (scl[wv][b3 + 0] + scl[wv][b3 + 3]));
        py = wout * (0.5f * (scl[wv][b3 + 1] + scl[wv][b3 + 4]));
        pz = wout * (0.5f * (scl[wv][b3 + 2] + scl[wv][b3 + 5]));
        out_w[(size_t)r * NSM1 + lane] = wout;
    }
#pragma unroll
    for (int off = 32; off; off >>= 1) {
        px += __shfl_xor(px, off);
        py += __shfl_xor(py, off);
        pz += __shfl_xor(pz, off);
    }
    if (lane == 0) {
        const float gmin = __uint_as_float(ws[0]);
        const float gmax = __uint_as_float(ws[1]);
        float cd = dsum / wt;
        if (!(cd == cd)) cd = gmax;                 // NaN -> inf -> clip to max
        cd = fminf(fmaxf(cd, gmin), gmax);
        out_depth[r] = cd;
        out_wt[r]    = wt;
        out_xyz[(size_t)r * 3 + 0] = px;
        out_xyz[(size_t)r * 3 + 1] = py;
        out_xyz[(size_t)r * 3 + 2] = pz;
    }
}

extern "C" void kernel_launch(void* const* d_in, const int* in_sizes, int n_in,
                              void* d_out, int out_size, void* d_ws, size_t ws_size,
                              hipStream_t stream) {
    const float* colors    = (const float*)d_in[0];
    const float* densities = (const float*)d_in[1];
    const float* depths    = (const float*)d_in[2];
    const float* sc        = (const float*)d_in[3];

    const int nrays = in_sizes[1] / NS;   // densities is [B,R,S,1]

    float* out       = (float*)d_out;
    float* out_rgb   = out;                                   // [nrays, 32]
    float* out_depth = out_rgb + (size_t)nrays * NC;          // [nrays, 1]
    float* out_w     = out_depth + nrays;                     // [nrays, 47]
    float* out_xyz   = out_w + (size_t)nrays * NSM1;          // [nrays, 3]
    float* out_wt    = out_xyz + (size_t)nrays * 3;           // [nrays, 1]

    unsigned int* ws = (unsigned int*)d_ws;

    hipLaunchKernelGGL(init_ws_kernel, dim3(1), dim3(1), 0, stream, ws);
    hipLaunchKernelGGL(depth_minmax_kernel,
                       dim3((nrays + 255) / 256), dim3(256), 0, stream,
                       depths, ws, nrays);
    hipLaunchKernelGGL(raymarch_kernel,
                       dim3((nrays + WPB - 1) / WPB), dim3(WPB * 64), 0, stream,
                       colors, densities, depths, sc, ws,
                       out_rgb, out_depth, out_w, out_xyz, out_wt, nrays);
}

// Round 2
// 49.025 us; speedup vs baseline: 1.1907x; 1.1907x over previous
//
#include <hip/hip_runtime.h>

#define NS   48          // samples per ray
#define NSM1 47          // segments per ray
#define NC   32          // color channels
#define WPB  8           // waves (rays) per block -> 512 threads

// ===================== fallback path (tiny ws) ============================
__global__ void init_ws_kernel(unsigned int* ws) {
    ws[0] = 0x7f800000u;   // +inf bits (uint order == float order for +floats)
    ws[1] = 0u;
}

__global__ void depth_minmax_kernel(const float* __restrict__ depths,
                                    unsigned int* __restrict__ ws, int nrays) {
    int t = blockIdx.x * blockDim.x + threadIdx.x;
    float mn = __uint_as_float(0x7f800000u);
    float mx = 0.0f;
    if (t < nrays) {
        mn = depths[(size_t)t * NS];
        mx = depths[(size_t)t * NS + (NS - 1)];
    }
#pragma unroll
    for (int off = 32; off; off >>= 1) {
        mn = fminf(mn, __shfl_xor(mn, off));
        mx = fmaxf(mx, __shfl_xor(mx, off));
    }
    if ((threadIdx.x & 63) == 0) {
        atomicMin(ws + 0, __float_as_uint(mn));
        atomicMax(ws + 1, __float_as_uint(mx));
    }
}

// ===================== main ray-march kernel ===============================
__launch_bounds__(WPB * 64)
__global__ void raymarch_kernel(const float* __restrict__ colors,
                                const float* __restrict__ densities,
                                const float* __restrict__ depths,
                                const float* __restrict__ sc,
                                float2* __restrict__ partials,   // d_ws
                                int use_partials,
                                float* __restrict__ out_rgb,
                                float* __restrict__ out_depth,
                                float* __restrict__ out_w,
                                float* __restrict__ out_xyz,
                                float* __restrict__ out_wt,
                                int nrays) {
    __shared__ float wlds[WPB][52];    // 49 used: [0]=0, [1..47]=w, [48]=0
    __shared__ float scl[WPB][146];    // 144 used: per-ray sample coords
    __shared__ float smn[WPB], smx[WPB];

    const int lane = threadIdx.x & 63;
    const int wv   = threadIdx.x >> 6;
    const int r    = blockIdx.x * WPB + wv;
    const bool active = (r < nrays);
    const int rr = active ? r : (nrays - 1);

    // ---- issue the big color loads FIRST (latency hides under phase A) ---
    const float4* colp = (const float4*)(colors + (size_t)rr * (NS * NC));
    float4 cv[6];
#pragma unroll
    for (int t = 0; t < 6; ++t) cv[t] = colp[t * 64 + lane];

    // ---- stage sample coords (independent of weights) ---------------------
    const size_t scbase = (size_t)rr * (NS * 3);
#pragma unroll
    for (int i = 0; i < 3; ++i) {
        const int idx = lane + i * 64;
        if (idx < NS * 3) scl[wv][idx] = sc[scbase + idx];
    }

    // ---- phase A: per-segment alpha / transmittance / weights -----------
    const size_t rbase = (size_t)rr * NS;
    float d = 0.0f, de = 0.0f;
    if (lane < NS) {
        d  = depths[rbase + lane];
        de = densities[rbase + lane];
    }
    const float d1  = __shfl_down(d, 1);
    const float de1 = __shfl_down(de, 1);
    const float dmax = __shfl(d, NSM1);     // ray max depth (sorted)

    float alpha = 0.0f, dmid = 0.0f, f = 1.0f;
    if (lane < NSM1) {
        const float delta = d1 - d;
        dmid = 0.5f * (d + d1);
        const float x  = 0.5f * (de + de1) - 1.0f;
        const float sp = fmaxf(x, 0.0f) + __logf(1.0f + __expf(-fabsf(x)));
        alpha = 1.0f - __expf(-sp * delta);
        f = 1.0f - alpha + 1e-10f;
    }

    // exclusive prefix product of f -> transmittance
    float g = __shfl_up(f, 1);
    if (lane == 0) g = 1.0f;
#pragma unroll
    for (int off = 1; off < 64; off <<= 1) {
        const float v = __shfl_up(g, off);
        if (lane >= off) g *= v;
    }
    const float wgt = (lane < NSM1) ? alpha * g : 0.0f;

    // weight_total and depth numerator
    float wt = wgt, dsum = wgt * dmid;
#pragma unroll
    for (int off = 32; off; off >>= 1) {
        wt   += __shfl_xor(wt, off);
        dsum += __shfl_xor(dsum, off);
    }

    // ---- stage per-ray weights + per-wave depth minmax --------------------
    if (lane < NSM1) wlds[wv][lane + 1] = wgt;
    if (lane == 0) {
        wlds[wv][0] = 0.0f; wlds[wv][NS] = 0.0f;
        smn[wv] = active ? d    : __uint_as_float(0x7f800000u);
        smx[wv] = active ? dmax : -__uint_as_float(0x7f800000u);
    }
    __syncthreads();

    if (use_partials && threadIdx.x == 0) {
        float mn = smn[0], mx = smx[0];
#pragma unroll
        for (int w = 1; w < WPB; ++w) {
            mn = fminf(mn, smn[w]);
            mx = fmaxf(mx, smx[w]);
        }
        partials[blockIdx.x] = make_float2(mn, mx);
    }

    // ---- colors: accumulate hoisted loads ---------------------------------
    // rgb[c] = sum_j col[j][c] * 0.5*(w[j-1]+w[j])
    const int soff = lane >> 3;
    float4 acc = make_float4(0.f, 0.f, 0.f, 0.f);
#pragma unroll
    for (int t = 0; t < 6; ++t) {
        const int j = t * 8 + soff;
        const float a = 0.5f * (wlds[wv][j] + wlds[wv][j + 1]);
        acc.x = fmaf(a, cv[t].x, acc.x);
        acc.y = fmaf(a, cv[t].y, acc.y);
        acc.z = fmaf(a, cv[t].z, acc.z);
        acc.w = fmaf(a, cv[t].w, acc.w);
    }
#pragma unroll
    for (int off = 8; off < 64; off <<= 1) {
        acc.x += __shfl_xor(acc.x, off);
        acc.y += __shfl_xor(acc.y, off);
        acc.z += __shfl_xor(acc.z, off);
        acc.w += __shfl_xor(acc.w, off);
    }
    if (active && lane < 8) {
        float4 o;
        o.x = fmaf(acc.x, 2.0f, -1.0f);
        o.y = fmaf(acc.y, 2.0f, -1.0f);
        o.z = fmaf(acc.z, 2.0f, -1.0f);
        o.w = fmaf(acc.w, 2.0f, -1.0f);
        ((float4*)out_rgb)[(size_t)r * (NC / 4) + lane] = o;
    }

    // ---- weights_out, xyz, depth, weight_total ---------------------------
    float px = 0.f, py = 0.f, pz = 0.f;
    if (lane < NSM1) {
        const float wout = wgt + ((lane == NSM1 - 1) ? (1.0f - wt) : 0.0f);
        const int b3 = 3 * lane;
        px = wout * (0.5f * (scl[wv][b3 + 0] + scl[wv][b3 + 3]));
        py = wout * (0.5f * (scl[wv][b3 + 1] + scl[wv][b3 + 4]));
        pz = wout * (0.5f * (scl[wv][b3 + 2] + scl[wv][b3 + 5]));
        if (active) out_w[(size_t)r * NSM1 + lane] = wout;
    }
#pragma unroll
    for (int off = 32; off; off >>= 1) {
        px += __shfl_xor(px, off);
        py += __shfl_xor(py, off);
        pz += __shfl_xor(pz, off);
    }
    if (active && lane == 0) {
        out_depth[r] = dsum / wt;          // unclamped; fixup kernel clamps
        out_wt[r]    = wt;
        out_xyz[(size_t)r * 3 + 0] = px;
        out_xyz[(size_t)r * 3 + 1] = py;
        out_xyz[(size_t)r * 3 + 2] = pz;
    }
}

// ===================== fixup: global minmax reduce + depth clamp ===========
__launch_bounds__(256)
__global__ void fixup_kernel(const void* __restrict__ wsv, int nparts,
                             int use_partials,
                             float* __restrict__ out_depth, int nrays) {
    __shared__ float smn[4], smx[4];
    const int tid  = threadIdx.x;
    const int lane = tid & 63;
    const int wv   = tid >> 6;

    float gmn, gmx;
    if (use_partials) {
        const float2* partials = (const float2*)wsv;
        float mn = __uint_as_float(0x7f800000u);
        float mx = -mn;
        for (int i = tid; i < nparts; i += 256) {
            const float2 p = partials[i];
            mn = fminf(mn, p.x);
            mx = fmaxf(mx, p.y);
        }
#pragma unroll
        for (int off = 32; off; off >>= 1) {
            mn = fminf(mn, __shfl_xor(mn, off));
            mx = fmaxf(mx, __shfl_xor(mx, off));
        }
        if (lane == 0) { smn[wv] = mn; smx[wv] = mx; }
        __syncthreads();
        if (tid == 0) {
#pragma unroll
            for (int w = 1; w < 4; ++w) {
                smn[0] = fminf(smn[0], smn[w]);
                smx[0] = fmaxf(smx[0], smx[w]);
            }
        }
        __syncthreads();
        gmn = smn[0];
        gmx = smx[0];
    } else {
        const unsigned int* wsu = (const unsigned int*)wsv;
        gmn = __uint_as_float(wsu[0]);
        gmx = __uint_as_float(wsu[1]);
    }

    for (int i = blockIdx.x * 256 + tid; i < nrays; i += gridDim.x * 256) {
        float cd = out_depth[i];
        if (!(cd == cd)) cd = gmx;                    // NaN -> inf -> clip max
        out_depth[i] = fminf(fmaxf(cd, gmn), gmx);
    }
}

extern "C" void kernel_launch(void* const* d_in, const int* in_sizes, int n_in,
                              void* d_out, int out_size, void* d_ws, size_t ws_size,
                              hipStream_t stream) {
    const float* colors    = (const float*)d_in[0];
    const float* densities = (const float*)d_in[1];
    const float* depths    = (const float*)d_in[2];
    const float* sc        = (const float*)d_in[3];

    const int nrays   = in_sizes[1] / NS;   // densities is [B,R,S,1]
    const int nblocks = (nrays + WPB - 1) / WPB;

    float* out       = (float*)d_out;
    float* out_rgb   = out;                                   // [nrays, 32]
    float* out_depth = out_rgb + (size_t)nrays * NC;          // [nrays, 1]
    float* out_w     = out_depth + nrays;                     // [nrays, 47]
    float* out_xyz   = out_w + (size_t)nrays * NSM1;          // [nrays, 3]
    float* out_wt    = out_xyz + (size_t)nrays * 3;           // [nrays, 1]

    const int use_partials = (ws_size >= (size_t)nblocks * sizeof(float2)) ? 1 : 0;

    if (!use_partials) {
        // tiny-ws fallback: atomic global minmax into ws[0..1]
        hipLaunchKernelGGL(init_ws_kernel, dim3(1), dim3(1), 0, stream,
                           (unsigned int*)d_ws);
        hipLaunchKernelGGL(depth_minmax_kernel,
                           dim3((nrays + 255) / 256), dim3(256), 0, stream,
                           depths, (unsigned int*)d_ws, nrays);
    }

    hipLaunchKernelGGL(raymarch_kernel,
                       dim3(nblocks), dim3(WPB * 64), 0, stream,
                       colors, densities, depths, sc,
                       (float2*)d_ws, use_partials,
                       out_rgb, out_depth, out_w, out_xyz, out_wt, nrays);

    hipLaunchKernelGGL(fixup_kernel, dim3(64), dim3(256), 0, stream,
                       d_ws, nblocks, use_partials, out_depth, nrays);
}

// Round 3
// 47.443 us; speedup vs baseline: 1.2304x; 1.0333x over previous
//
#include <hip/hip_runtime.h>

#define NS   48          // samples per ray
#define NSM1 47          // segments per ray
#define NC   32          // color channels
#define WPB  8           // waves (rays) per block -> 512 threads
#define MMB  64          // minmax pre-kernel blocks (== lanes in a wave!)

// ---------- pre-pass: global depth min/max -> 64 float2 partials ----------
// depths are sorted along S, so per-ray min = s[0], max = s[47].
__launch_bounds__(256)
__global__ void depth_minmax_partials(const float* __restrict__ depths,
                                      float2* __restrict__ partials,
                                      int nrays) {
    const int tid  = threadIdx.x;
    const int lane = tid & 63;
    const int wv   = tid >> 6;
    float mn = __uint_as_float(0x7f800000u);
    float mx = -mn;
    for (int r = blockIdx.x * 256 + tid; r < nrays; r += MMB * 256) {
        mn = fminf(mn, depths[(size_t)r * NS]);
        mx = fmaxf(mx, depths[(size_t)r * NS + NSM1]);
    }
#pragma unroll
    for (int off = 32; off; off >>= 1) {
        mn = fminf(mn, __shfl_xor(mn, off));
        mx = fmaxf(mx, __shfl_xor(mx, off));
    }
    __shared__ float smn[4], smx[4];
    if (lane == 0) { smn[wv] = mn; smx[wv] = mx; }
    __syncthreads();
    if (tid == 0) {
        mn = fminf(fminf(smn[0], smn[1]), fminf(smn[2], smn[3]));
        mx = fmaxf(fmaxf(smx[0], smx[1]), fmaxf(smx[2], smx[3]));
        partials[blockIdx.x] = make_float2(mn, mx);
    }
}

// ---------------- main ray-march compositing kernel ------------------------
__launch_bounds__(WPB * 64)
__global__ void raymarch_kernel(const float* __restrict__ colors,
                                const float* __restrict__ densities,
                                const float* __restrict__ depths,
                                const float* __restrict__ sc,
                                const float2* __restrict__ partials,
                                float* __restrict__ out_rgb,
                                float* __restrict__ out_depth,
                                float* __restrict__ out_w,
                                float* __restrict__ out_xyz,
                                float* __restrict__ out_wt,
                                int nrays) {
    __shared__ float wlds[WPB][52];    // 49 used: [0]=0, [1..47]=w, [48]=0
    __shared__ float scl[WPB][146];    // 144 used: per-ray sample coords

    const int lane = threadIdx.x & 63;
    const int wv   = threadIdx.x >> 6;
    const int r    = blockIdx.x * WPB + wv;
    const bool active = (r < nrays);
    const int rr = active ? r : (nrays - 1);

    // ---- issue long-latency loads FIRST ----------------------------------
    const float2 pp = partials[lane];            // 64 entries == 64 lanes
    const float4* colp = (const float4*)(colors + (size_t)rr * (NS * NC));
    float4 cv[6];
#pragma unroll
    for (int t = 0; t < 6; ++t) cv[t] = colp[t * 64 + lane];

    const size_t scbase = (size_t)rr * (NS * 3);
#pragma unroll
    for (int i = 0; i < 3; ++i) {
        const int idx = lane + i * 64;
        if (idx < NS * 3) scl[wv][idx] = sc[scbase + idx];
    }

    // ---- phase A: per-segment alpha / transmittance / weights -----------
    const size_t rbase = (size_t)rr * NS;
    float d = 0.0f, de = 0.0f;
    if (lane < NS) {
        d  = depths[rbase + lane];
        de = densities[rbase + lane];
    }
    const float d1  = __shfl_down(d, 1);
    const float de1 = __shfl_down(de, 1);

    float alpha = 0.0f, dmid = 0.0f, f = 1.0f;
    if (lane < NSM1) {
        const float delta = d1 - d;
        dmid = 0.5f * (d + d1);
        const float x  = 0.5f * (de + de1) - 1.0f;
        const float sp = fmaxf(x, 0.0f) + __logf(1.0f + __expf(-fabsf(x)));
        alpha = 1.0f - __expf(-sp * delta);
        f = 1.0f - alpha + 1e-10f;
    }

    // exclusive prefix product of f -> transmittance
    float g = __shfl_up(f, 1);
    if (lane == 0) g = 1.0f;
#pragma unroll
    for (int off = 1; off < 64; off <<= 1) {
        const float v = __shfl_up(g, off);
        if (lane >= off) g *= v;
    }
    const float wgt = (lane < NSM1) ? alpha * g : 0.0f;

    // weight_total and depth numerator
    float wt = wgt, dsum = wgt * dmid;
#pragma unroll
    for (int off = 32; off; off >>= 1) {
        wt   += __shfl_xor(wt, off);
        dsum += __shfl_xor(dsum, off);
    }

    // ---- stage per-ray weights ------------------------------------------
    if (lane < NSM1) wlds[wv][lane + 1] = wgt;
    if (lane == 0) { wlds[wv][0] = 0.0f; wlds[wv][NS] = 0.0f; }
    __syncthreads();

    // ---- colors: accumulate hoisted loads ---------------------------------
    // rgb[c] = sum_j col[j][c] * 0.5*(w[j-1]+w[j])
    const int soff = lane >> 3;
    float4 acc = make_float4(0.f, 0.f, 0.f, 0.f);
#pragma unroll
    for (int t = 0; t < 6; ++t) {
        const int j = t * 8 + soff;
        const float a = 0.5f * (wlds[wv][j] + wlds[wv][j + 1]);
        acc.x = fmaf(a, cv[t].x, acc.x);
        acc.y = fmaf(a, cv[t].y, acc.y);
        acc.z = fmaf(a, cv[t].z, acc.z);
        acc.w = fmaf(a, cv[t].w, acc.w);
    }
#pragma unroll
    for (int off = 8; off < 64; off <<= 1) {
        acc.x += __shfl_xor(acc.x, off);
        acc.y += __shfl_xor(acc.y, off);
        acc.z += __shfl_xor(acc.z, off);
        acc.w += __shfl_xor(acc.w, off);
    }
    if (active && lane < 8) {
        float4 o;
        o.x = fmaf(acc.x, 2.0f, -1.0f);
        o.y = fmaf(acc.y, 2.0f, -1.0f);
        o.z = fmaf(acc.z, 2.0f, -1.0f);
        o.w = fmaf(acc.w, 2.0f, -1.0f);
        ((float4*)out_rgb)[(size_t)r * (NC / 4) + lane] = o;
    }

    // ---- weights_out, xyz ------------------------------------------------
    float px = 0.f, py = 0.f, pz = 0.f;
    if (lane < NSM1) {
        const float wout = wgt + ((lane == NSM1 - 1) ? (1.0f - wt) : 0.0f);
        const int b3 = 3 * lane;
        px = wout * (0.5f * (scl[wv][b3 + 0] + scl[wv][b3 + 3]));
        py = wout * (0.5f * (scl[wv][b3 + 1] + scl[wv][b3 + 4]));
        pz = wout * (0.5f * (scl[wv][b3 + 2] + scl[wv][b3 + 5]));
        if (active) out_w[(size_t)r * NSM1 + lane] = wout;
    }
#pragma unroll
    for (int off = 32; off; off >>= 1) {
        px += __shfl_xor(px, off);
        py += __shfl_xor(py, off);
        pz += __shfl_xor(pz, off);
    }

    // ---- global depth minmax reduce (from hoisted partials) + tail write --
    float gmn = pp.x, gmx = pp.y;
#pragma unroll
    for (int off = 32; off; off >>= 1) {
        gmn = fminf(gmn, __shfl_xor(gmn, off));
        gmx = fmaxf(gmx, __shfl_xor(gmx, off));
    }
    if (active && lane == 0) {
        float cd = dsum / wt;
        if (!(cd == cd)) cd = gmx;                 // NaN -> inf -> clip to max
        cd = fminf(fmaxf(cd, gmn), gmx);
        out_depth[r] = cd;
        out_wt[r]    = wt;
        out_xyz[(size_t)r * 3 + 0] = px;
        out_xyz[(size_t)r * 3 + 1] = py;
        out_xyz[(size_t)r * 3 + 2] = pz;
    }
}

extern "C" void kernel_launch(void* const* d_in, const int* in_sizes, int n_in,
                              void* d_out, int out_size, void* d_ws, size_t ws_size,
                              hipStream_t stream) {
    const float* colors    = (const float*)d_in[0];
    const float* densities = (const float*)d_in[1];
    const float* depths    = (const float*)d_in[2];
    const float* sc        = (const float*)d_in[3];

    const int nrays   = in_sizes[1] / NS;   // densities is [B,R,S,1]
    const int nblocks = (nrays + WPB - 1) / WPB;

    float* out       = (float*)d_out;
    float* out_rgb   = out;                                   // [nrays, 32]
    float* out_depth = out_rgb + (size_t)nrays * NC;          // [nrays, 1]
    float* out_w     = out_depth + nrays;                     // [nrays, 47]
    float* out_xyz   = out_w + (size_t)nrays * NSM1;          // [nrays, 3]
    float* out_wt    = out_xyz + (size_t)nrays * 3;           // [nrays, 1]

    float2* partials = (float2*)d_ws;       // needs 64*8 = 512 B of ws

    hipLaunchKernelGGL(depth_minmax_partials, dim3(MMB), dim3(256), 0, stream,
                       depths, partials, nrays);
    hipLaunchKernelGGL(raymarch_kernel, dim3(nblocks), dim3(WPB * 64), 0, stream,
                       colors, densities, depths, sc, partials,
                       out_rgb, out_depth, out_w, out_xyz, out_wt, nrays);
}